// Round 3
// baseline (1068.523 us; speedup 1.0000x reference)
//
#include <hip/hip_runtime.h>
#include <math.h>

#define E_EDGES 200000
#define N_NODES 10000
#define FDIM    128

typedef __attribute__((ext_vector_type(8))) short  short8;
typedef __attribute__((ext_vector_type(4))) float  float4v;

// ws layout: bf16 weights (ushort units), then sort scratch (byte offsets).
#define WT1_OFF   0            // Wt1[128][256]
#define WTW1_OFF  32768        // Wtw1[128][128]
#define WT2_OFF   49152       // Wt2[640][128]
#define WTW2_OFF  131072       // Wtw2[640][128]
#define W_TOTAL   212992       // ushorts = 425,984 bytes
#define CNT_BYTE  425984       // counts[10000] int
#define CUR_BYTE  465984       // cursor[10000] int
#define PERM_BYTE 505984       // perm[200000] int  (ends at 1,305,984 B)

#define EQ_OUT_SZ   (N_NODES * FDIM * 3)   // 3,840,000
#define INV_OUT_SZ  (N_NODES * FDIM)       // 1,280,000

__device__ __forceinline__ unsigned short f2bf(float x) {
    union { float f; unsigned u; } v; v.f = x;
    unsigned r = v.u + 0x7fffu + ((v.u >> 16) & 1u);
    return (unsigned short)(r >> 16);
}
__device__ __forceinline__ float bf2f(unsigned short h) {
    union { unsigned u; float f; } v; v.u = ((unsigned)h) << 16; return v.f;
}

// ---------------- prep: transpose weights to bf16 [n][k] ----------------
__global__ void prep_weights(const float* __restrict__ phiW1,
                             const float* __restrict__ wW1,
                             const float* __restrict__ phiW2,
                             const float* __restrict__ wW2,
                             unsigned short* __restrict__ ws) {
    int t = blockIdx.x * 256 + threadIdx.x;
    if (t < 32768) {
        int n = t >> 8, k = t & 255;
        ws[WT1_OFF + t] = f2bf(phiW1[k * 128 + n]);
    } else if (t < 49152) {
        int i = t - 32768; int n = i >> 7, k = i & 127;
        ws[WTW1_OFF + i] = f2bf(wW1[k * 128 + n]);
    } else if (t < 131072) {
        int i = t - 49152; int n = i >> 7, k = i & 127;
        ws[WT2_OFF + i] = f2bf(phiW2[k * 640 + n]);
    } else if (t < W_TOTAL) {
        int i = t - 131072; int n = i >> 7, k = i & 127;
        ws[WTW2_OFF + i] = f2bf(wW2[k * 640 + n]);
    }
}

// ---------------- counting sort by dst ----------------
__global__ void zero_counts(int* __restrict__ counts) {
    int t = blockIdx.x * 256 + threadIdx.x;
    if (t < N_NODES) counts[t] = 0;
}
__global__ void hist_kernel(const int* __restrict__ eidx, int* __restrict__ counts) {
    int e = blockIdx.x * 256 + threadIdx.x;
    if (e < E_EDGES) atomicAdd(&counts[eidx[E_EDGES + e]], 1);
}
__global__ __launch_bounds__(1024)
void scan_kernel(const int* __restrict__ counts, int* __restrict__ cursor) {
    __shared__ int sums[1024];
    const int t = threadIdx.x;
    const int base = t * 10;
    int local[10];
    int s = 0;
    #pragma unroll
    for (int j = 0; j < 10; ++j) {
        int b = base + j;
        int v = (b < N_NODES) ? counts[b] : 0;
        local[j] = s; s += v;
    }
    sums[t] = s;
    __syncthreads();
    for (int off = 1; off < 1024; off <<= 1) {
        int v = (t >= off) ? sums[t - off] : 0;
        __syncthreads();
        sums[t] += v;
        __syncthreads();
    }
    int pre = (t > 0) ? sums[t - 1] : 0;
    #pragma unroll
    for (int j = 0; j < 10; ++j) {
        int b = base + j;
        if (b < N_NODES) cursor[b] = pre + local[j];
    }
}
__global__ void scatter_kernel(const int* __restrict__ eidx,
                               int* __restrict__ cursor, int* __restrict__ perm) {
    int e = blockIdx.x * 256 + threadIdx.x;
    if (e < E_EDGES) {
        int d = eidx[E_EDGES + e];
        int pos = atomicAdd(&cursor[d], 1);
        perm[pos] = e;
    }
}

// ---------------- init: out[0:eq] = eq, out[eq:+inv] = inv ----------------
__global__ void init_out_k(const float* __restrict__ eq,
                           const float* __restrict__ inv,
                           float* __restrict__ out) {
    int t = blockIdx.x * 256 + threadIdx.x;
    if (t < EQ_OUT_SZ / 4) {
        ((float4v*)out)[t] = ((const float4v*)eq)[t];
    } else {
        int u = t - EQ_OUT_SZ / 4;
        ((float4v*)(out + EQ_OUT_SZ))[u] = ((const float4v*)inv)[u];
    }
}

// ---------------- fused edge kernel: 32 sorted edges / block ----------------
// launch_bounds(256,4): 4 waves/EU -> <=128 VGPR, 4 blocks/CU (LDS ~27KB allows 6)
__global__ __launch_bounds__(256, 4)
void edge_kernel(const int*   __restrict__ eidx,
                 const float* __restrict__ node_inv,
                 const float* __restrict__ eqf,
                 const float* __restrict__ edge_inv,
                 const float* __restrict__ dist,
                 const float* __restrict__ dir,
                 const float* __restrict__ phi_b1,
                 const float* __restrict__ phi_b2,
                 const float* __restrict__ w_b1,
                 const float* __restrict__ w_b2,
                 const unsigned short* __restrict__ wsW,
                 const int* __restrict__ perm,
                 float* __restrict__ out) {
    // AH[0]: A1a (node_inv[src]) in phase 1, then H1 (overlay, barrier-protected)
    // AH[1]: A2  (pos.enc.)      in phase 1, then H2
    __shared__ unsigned short AH[2][32][136];
    __shared__ unsigned short A1b[32][136];   // edge_inv bf16 (live through epilogue)
    __shared__ int   s_e[32], s_src[32], s_dst[32];
    __shared__ float s_dir[32][3];

    const int tid = threadIdx.x;
    const int p0  = blockIdx.x * 32;

    if (tid < 32) {
        int e = perm[p0 + tid];
        s_e[tid]   = e;
        s_src[tid] = eidx[e];
        s_dst[tid] = eidx[E_EDGES + e];
        s_dir[tid][0] = dir[e * 3 + 0];
        s_dir[tid][1] = dir[e * 3 + 1];
        s_dir[tid][2] = dir[e * 3 + 2];
    }
    __syncthreads();

    // ---- stage A1a (node_inv[src]), A1b (edge_inv[e]), A2 (PE) as bf16 ----
    {
        const int i   = tid >> 3;        // row 0..31
        const int seg = tid & 7;         // 0..7
        const int e   = s_e[i];
        const int k0  = seg * 32;
        const float* base = (k0 < 128)
            ? (node_inv + (size_t)s_src[i] * 128 + k0)
            : (edge_inv + (size_t)e * 128 + (k0 - 128));
        unsigned short* dst_ls = (k0 < 128) ? &AH[0][i][k0] : &A1b[i][k0 - 128];
        #pragma unroll
        for (int j = 0; j < 4; ++j) {
            float4v v0 = *(const float4v*)(base + j * 8);
            float4v v1 = *(const float4v*)(base + j * 8 + 4);
            short8 sv;
            #pragma unroll
            for (int u = 0; u < 4; ++u) {
                sv[u]     = (short)f2bf(v0[u]);
                sv[u + 4] = (short)f2bf(v1[u]);
            }
            *(short8*)(dst_ls + j * 8) = sv;
        }
        const float d   = dist[e];
        const float cst = 3.14159265358979323846f / 10.0f;
        #pragma unroll
        for (int j = 0; j < 2; ++j) {
            short8 sv;
            #pragma unroll
            for (int u = 0; u < 8; ++u) {
                int f = seg * 16 + j * 8 + u;
                float val = (f < 64) ? __sinf(d * (float)f * cst)
                                     : __cosf(d * (float)(f - 64) * cst);
                sv[u] = (short)f2bf(val);
            }
            *(short8*)&AH[1][i][seg * 16 + j * 8] = sv;
        }
    }
    __syncthreads();

    const int wv   = tid >> 6;
    const int ln   = tid & 63;
    const int l16  = ln & 15;
    const int quad = ln >> 4;

    const unsigned short* Wt1  = wsW + WT1_OFF;
    const unsigned short* Wtw1 = wsW + WTW1_OFF;
    const unsigned short* Wt2  = wsW + WT2_OFF;
    const unsigned short* Wtw2 = wsW + WTW2_OFF;

    const float4v zero4 = {0.f, 0.f, 0.f, 0.f};

    // ---- phase 1: H1 = silu(A1 @ phiW1 + b1), H2 = silu(A2 @ wW1 + wb1) ----
    float4v acc1[2][2], acc2[2][2];
    #pragma unroll
    for (int rt = 0; rt < 2; ++rt)
        #pragma unroll
        for (int ct = 0; ct < 2; ++ct) { acc1[rt][ct] = zero4; acc2[rt][ct] = zero4; }

    #pragma unroll
    for (int kk = 0; kk < 4; ++kk) {        // K 0..127 (node part, from AH[0])
        const int k = kk * 32 + quad * 8;
        short8 a0 = *(const short8*)&AH[0][l16][k];
        short8 a1 = *(const short8*)&AH[0][16 + l16][k];
        #pragma unroll
        for (int ct = 0; ct < 2; ++ct) {
            const int n = wv * 32 + ct * 16 + l16;
            short8 b = *(const short8*)&Wt1[n * 256 + k];
            acc1[0][ct] = __builtin_amdgcn_mfma_f32_16x16x32_bf16(a0, b, acc1[0][ct], 0, 0, 0);
            acc1[1][ct] = __builtin_amdgcn_mfma_f32_16x16x32_bf16(a1, b, acc1[1][ct], 0, 0, 0);
        }
    }
    #pragma unroll
    for (int kk = 0; kk < 4; ++kk) {        // K 128..255 (edge part, from A1b)
        const int k = kk * 32 + quad * 8;
        short8 a0 = *(const short8*)&A1b[l16][k];
        short8 a1 = *(const short8*)&A1b[16 + l16][k];
        #pragma unroll
        for (int ct = 0; ct < 2; ++ct) {
            const int n = wv * 32 + ct * 16 + l16;
            short8 b = *(const short8*)&Wt1[n * 256 + 128 + k];
            acc1[0][ct] = __builtin_amdgcn_mfma_f32_16x16x32_bf16(a0, b, acc1[0][ct], 0, 0, 0);
            acc1[1][ct] = __builtin_amdgcn_mfma_f32_16x16x32_bf16(a1, b, acc1[1][ct], 0, 0, 0);
        }
    }
    #pragma unroll
    for (int kk = 0; kk < 4; ++kk) {        // PE, from AH[1]
        const int k = kk * 32 + quad * 8;
        short8 a0 = *(const short8*)&AH[1][l16][k];
        short8 a1 = *(const short8*)&AH[1][16 + l16][k];
        #pragma unroll
        for (int ct = 0; ct < 2; ++ct) {
            const int n = wv * 32 + ct * 16 + l16;
            short8 b = *(const short8*)&Wtw1[n * 128 + k];
            acc2[0][ct] = __builtin_amdgcn_mfma_f32_16x16x32_bf16(a0, b, acc2[0][ct], 0, 0, 0);
            acc2[1][ct] = __builtin_amdgcn_mfma_f32_16x16x32_bf16(a1, b, acc2[1][ct], 0, 0, 0);
        }
    }
    __syncthreads();      // all A reads done -> safe to overlay H into AH

    // silu + store H (C/D: col = l16, row = quad*4 + reg)
    #pragma unroll
    for (int ct = 0; ct < 2; ++ct) {
        const int n = wv * 32 + ct * 16 + l16;
        const float b1v  = phi_b1[n];
        const float bw1v = w_b1[n];
        #pragma unroll
        for (int rt = 0; rt < 2; ++rt)
            #pragma unroll
            for (int r = 0; r < 4; ++r) {
                const int row = rt * 16 + quad * 4 + r;
                float x = acc1[rt][ct][r] + b1v;
                AH[0][row][n] = f2bf(x / (1.f + __expf(-x)));
                float y = acc2[rt][ct][r] + bw1v;
                AH[1][row][n] = f2bf(y / (1.f + __expf(-y)));
            }
    }
    __syncthreads();      // H ready; NO more barriers below

    // ---- phase 2: 4 chunks of 32 features; no barriers, register-only epilogue ----
    float* eq_out   = out;
    float* inv_out  = out + EQ_OUT_SZ;
    float* edge_out = out + EQ_OUT_SZ + INV_OUT_SZ;

    const int wvl = wv & 1;      // column half within 32-feature chunk
    const int wvh = wv >> 1;     // row half (edges 0-15 / 16-31)
    const int row0 = wvh * 16 + quad * 4;

    // hoist A-fragments (fc/g-invariant)
    short8 ha[4], hb[4];
    #pragma unroll
    for (int kk = 0; kk < 4; ++kk) {
        const int k = kk * 32 + quad * 8;
        ha[kk] = *(const short8*)&AH[0][wvh * 16 + l16][k];
        hb[kk] = *(const short8*)&AH[1][wvh * 16 + l16][k];
    }

    const int fl = wvl * 16 + l16;      // 0..31 within chunk

    #pragma unroll
    for (int fc = 0; fc < 4; ++fc) {
        const int fg = fc * 32 + fl;
        // prefetch eqf gathers for this fc BEFORE the GEMMs (covered by MFMA)
        float sx[4], sy[4], sz[4], dxx[4], dyy[4], dzz[4];
        #pragma unroll
        for (int r = 0; r < 4; ++r) {
            const int row = row0 + r;
            const float* se = eqf + ((size_t)s_src[row] * 128 + fg) * 3;
            const float* dq = eqf + ((size_t)s_dst[row] * 128 + fg) * 3;
            sx[r] = se[0]; sy[r] = se[1]; sz[r] = se[2];
            dxx[r] = dq[0]; dyy[r] = dq[1]; dzz[r] = dq[2];
        }
        float4v mv[5];
        #pragma unroll
        for (int g = 0; g < 5; ++g) {
            const int n = g * 128 + fc * 32 + wvl * 16 + l16;
            float4v p1 = zero4, p2 = zero4;
            #pragma unroll
            for (int kk = 0; kk < 4; ++kk) {
                const int k = kk * 32 + quad * 8;
                short8 b1f = *(const short8*)&Wt2[n * 128 + k];
                short8 b2f = *(const short8*)&Wtw2[n * 128 + k];
                p1 = __builtin_amdgcn_mfma_f32_16x16x32_bf16(ha[kk], b1f, p1, 0, 0, 0);
                p2 = __builtin_amdgcn_mfma_f32_16x16x32_bf16(hb[kk], b2f, p2, 0, 0, 0);
            }
            const float b2v  = phi_b2[n];
            const float bw2v = w_b2[n];
            mv[g] = (p1 + b2v) * (p2 + bw2v);
        }
        // epilogue: in-register run compression over the quad's 4 sorted rows
        float ax = 0.f, ay = 0.f, az = 0.f, aw = 0.f;
        int prev = s_dst[row0];
        #pragma unroll
        for (int r = 0; r < 4; ++r) {
            const int row = row0 + r;
            const float gate = mv[0][r];
            const float cpg  = mv[1][r];
            const float sc   = mv[2][r];
            const float dsv  = mv[3][r];
            const float dev  = mv[4][r];
            const float ex = s_dir[row][0], ey = s_dir[row][1], ez = s_dir[row][2];
            const float cx = ey * dzz[r] - ez * dyy[r];
            const float cy = ez * dxx[r] - ex * dzz[r];
            const float cz = ex * dyy[r] - ey * dxx[r];
            const float vx = sc * ex + gate * sx[r] + cpg * cx;
            const float vy = sc * ey + gate * sy[r] + cpg * cy;
            const float vz = sc * ez + gate * sz[r] + cpg * cz;
            edge_out[(size_t)s_e[row] * 128 + fg] = bf2f(A1b[row][fg]) + dev;
            const int d = s_dst[row];
            if (d != prev) {
                atomicAdd(eq_out + ((size_t)prev * 128 + fg) * 3 + 0, ax);
                atomicAdd(eq_out + ((size_t)prev * 128 + fg) * 3 + 1, ay);
                atomicAdd(eq_out + ((size_t)prev * 128 + fg) * 3 + 2, az);
                atomicAdd(inv_out + (size_t)prev * 128 + fg, aw);
                ax = ay = az = aw = 0.f; prev = d;
            }
            ax += vx; ay += vy; az += vz; aw += dsv;
        }
        atomicAdd(eq_out + ((size_t)prev * 128 + fg) * 3 + 0, ax);
        atomicAdd(eq_out + ((size_t)prev * 128 + fg) * 3 + 1, ay);
        atomicAdd(eq_out + ((size_t)prev * 128 + fg) * 3 + 2, az);
        atomicAdd(inv_out + (size_t)prev * 128 + fg, aw);
    }
}

extern "C" void kernel_launch(void* const* d_in, const int* in_sizes, int n_in,
                              void* d_out, int out_size, void* d_ws, size_t ws_size,
                              hipStream_t stream) {
    const int*   eidx     = (const int*)d_in[0];
    const float* node_inv = (const float*)d_in[1];
    const float* eqf      = (const float*)d_in[2];
    const float* edge_inv = (const float*)d_in[3];
    const float* dist     = (const float*)d_in[4];
    const float* dir      = (const float*)d_in[5];
    const float* phi_W1   = (const float*)d_in[6];
    const float* phi_b1   = (const float*)d_in[7];
    const float* phi_W2   = (const float*)d_in[8];
    const float* phi_b2   = (const float*)d_in[9];
    const float* w_W1     = (const float*)d_in[10];
    const float* w_b1     = (const float*)d_in[11];
    const float* w_W2     = (const float*)d_in[12];
    const float* w_b2     = (const float*)d_in[13];
    float* out = (float*)d_out;
    unsigned short* wsW = (unsigned short*)d_ws;
    int* counts = (int*)((char*)d_ws + CNT_BYTE);
    int* cursor = (int*)((char*)d_ws + CUR_BYTE);
    int* perm   = (int*)((char*)d_ws + PERM_BYTE);

    zero_counts<<<(N_NODES + 255) / 256, 256, 0, stream>>>(counts);
    hist_kernel<<<(E_EDGES + 255) / 256, 256, 0, stream>>>(eidx, counts);
    scan_kernel<<<1, 1024, 0, stream>>>(counts, cursor);
    scatter_kernel<<<(E_EDGES + 255) / 256, 256, 0, stream>>>(eidx, cursor, perm);
    prep_weights<<<(W_TOTAL + 255) / 256, 256, 0, stream>>>(phi_W1, w_W1, phi_W2, w_W2, wsW);
    init_out_k<<<(EQ_OUT_SZ + INV_OUT_SZ) / 4 / 256, 256, 0, stream>>>(eqf, node_inv, out);
    edge_kernel<<<E_EDGES / 32, 256, 0, stream>>>(eidx, node_inv, eqf, edge_inv, dist, dir,
                                                  phi_b1, phi_b2, w_b1, w_b2, wsW, perm, out);
}